// Round 2
// baseline (5173.705 us; speedup 1.0000x reference)
//
#include <hip/hip_runtime.h>
#include <stdint.h>

// Problem constants
#define BB   128      // batch
#define LL   128      // latent dim
#define HH   1024     // hidden
#define G4   4096     // 4*H
#define TT   256      // time steps
#define PP   128      // output cols per step

#define NGB  64                  // gate blocks: each owns 16 hidden units (64 weight rows)
#define NFB  8                   // fc blocks: each owns 16 rows of W_fc
#define NB   (NGB + NFB)

typedef _Float16 half8  __attribute__((ext_vector_type(8)));
typedef float   floatx4 __attribute__((ext_vector_type(4)));
typedef unsigned long long u64t;

__device__ __forceinline__ float sigf(float x) {
  x = fminf(fmaxf(x, -30.f), 30.f);
  return 1.f / (1.f + __expf(-x));
}
__device__ __forceinline__ float tanhf_fast(float x) {
  x = fminf(fmaxf(x, -15.f), 15.f);
  float e = __expf(2.f * x);
  return (e - 1.f) / (e + 1.f);
}
__device__ __forceinline__ unsigned short f2h(float x) {
  _Float16 h = (_Float16)x;
  return __builtin_bit_cast(unsigned short, h);
}
// agent-scope write-through h store: at LLC once vmcnt(0) drains (which
// __syncthreads() does per-wave before s_barrier)
__device__ __forceinline__ void store_h(unsigned short* p, float x) {
  __hip_atomic_store(p, f2h(x), __ATOMIC_RELAXED, __HIP_MEMORY_SCOPE_AGENT);
}
// agent-scope relaxed atomic load: coherence-point (LLC) read, bypasses any
// stale L1/L2 copy. Same primitive the barrier poll uses — proven to observe
// remote-XCD writes with NO fence.
__device__ __forceinline__ u64t load_llc(const u64t* p) {
  return __hip_atomic_load(p, __ATOMIC_RELAXED, __HIP_MEMORY_SCOPE_AGENT);
}

// Flat monotonic per-step grid barrier with NO cache-maintenance ops.
// Release side: h stores are write-through agent-scope (at LLC once vmcnt
// drains, which we do before the arrival add). Acquire side: NOT NEEDED,
// because all cross-step reads (the h A-stream) are agent-scope atomic
// loads that read at the coherence point. The previous kernel's per-step
// fence(acquire,"agent") emitted buffer_inv sc1 — an L2 tag walk that must
// spare dirty lines — issued by all 72 blocks every step; that is the
// hypothesized ~8 us/step serial cost this version removes.
__device__ __forceinline__ void stepbar(unsigned* bar, unsigned target) {
  __syncthreads();
  if (threadIdx.x == 0) {
    asm volatile("s_waitcnt vmcnt(0)" ::: "memory");   // h stores at LLC
    __hip_atomic_fetch_add(bar, 1u, __ATOMIC_RELAXED, __HIP_MEMORY_SCOPE_AGENT);
    while (__hip_atomic_load(bar, __ATOMIC_RELAXED, __HIP_MEMORY_SCOPE_AGENT) < target)
      __builtin_amdgcn_s_sleep(1);
  }
  __syncthreads();
}

// gates0 = z @ w_ih^T + b_ih + b_hh   (step-0 gates; h0=c0=0, x=0 for t>=1)
__global__ void prep_gates0(const float* __restrict__ z, const float* __restrict__ w_ih,
                            const float* __restrict__ b_ih, const float* __restrict__ b_hh,
                            float* __restrict__ g0) {
  int j = blockIdx.x;     // 0..4095
  int b = threadIdx.x;    // 0..127
  const float* zr = z + b * LL;
  const float* wr = w_ih + (size_t)j * LL;
  float s = 0.f;
#pragma unroll 4
  for (int k = 0; k < LL; ++k) s += zr[k] * wr[k];
  g0[(size_t)b * G4 + j] = s + b_ih[j] + b_hh[j];
}

// Convert w_hh / W_fc to fp16 in the persistent kernel's LDS layout.
// Gate block bid owns units u = bid*16 .. bid*16+15; LDS rows (tile*16+nl) for
// tile 0..3 = gates i,g,f,o of unit nl. Each row's 8-elem k-chunks are
// XOR-swizzled by (nl&7) so the wave's B-reads are same-bank-free.
__global__ void prep_weights(const float* __restrict__ w_hh, const float* __restrict__ W_fc,
                             unsigned short* __restrict__ wbuf) {
  int R = blockIdx.x;                 // 0..4223 (4096 gate rows + 128 fc rows)
  const float* src; int rsw;
  if (R < NGB * 64) {
    int bid = R >> 6, rr = R & 63, tile = rr >> 4, nl = rr & 15;
    int g = (tile == 0) ? 0 : (tile == 1) ? 2 : (tile == 2) ? 1 : 3;  // i,g,f,o
    src = w_hh + (size_t)(g * HH + bid * 16 + nl) * HH;
    rsw = nl & 7;
  } else {
    int p = R - NGB * 64;
    src = W_fc + (size_t)p * HH;
    rsw = p & 7;
  }
  unsigned short* dst = wbuf + (size_t)R * HH;
  for (int k = threadIdx.x; k < HH; k += blockDim.x) {
    int dk = (((k >> 3) ^ rsw) << 3) | (k & 7);
    _Float16 v = (_Float16)src[k];
    dst[dk] = __builtin_bit_cast(unsigned short, v);
  }
}

// One K=1024 MFMA pass: C[2 mtiles x NT ntiles], A streamed from global h via
// agent-scope atomic 8B loads (LLC-coherent, no fence needed), B from LDS
// (fp16, swizzled). PD-deep A prefetch per m-stream to hide LLC latency.
template <int NT, int PD>
__device__ __forceinline__ void gemm2xNT(const u64t* __restrict__ hb,
                                         const half8* __restrict__ w8,
                                         int abase0, int abase1,   // u64 units
                                         int quad, int rsw, int l15,
                                         floatx4 acc[2][NT]) {
  u64t ap0[PD][2], ap1[PD][2];
#pragma unroll
  for (int i = 0; i < PD; ++i) {
    ap0[i][0] = load_llc(hb + abase0 + i * 8);
    ap0[i][1] = load_llc(hb + abase0 + i * 8 + 1);
    ap1[i][0] = load_llc(hb + abase1 + i * 8);
    ap1[i][1] = load_llc(hb + abase1 + i * 8 + 1);
  }
#pragma unroll
  for (int kc = 0; kc < 32; ++kc) {
    union { u64t u[2]; half8 h; } a0u, a1u;
    a0u.u[0] = ap0[kc & (PD - 1)][0];
    a0u.u[1] = ap0[kc & (PD - 1)][1];
    a1u.u[0] = ap1[kc & (PD - 1)][0];
    a1u.u[1] = ap1[kc & (PD - 1)][1];
    if (kc < 32 - PD) {
      ap0[kc & (PD - 1)][0] = load_llc(hb + abase0 + (kc + PD) * 8);
      ap0[kc & (PD - 1)][1] = load_llc(hb + abase0 + (kc + PD) * 8 + 1);
      ap1[kc & (PD - 1)][0] = load_llc(hb + abase1 + (kc + PD) * 8);
      ap1[kc & (PD - 1)][1] = load_llc(hb + abase1 + (kc + PD) * 8 + 1);
    }
    int sw = (kc * 4 + quad) ^ rsw;
#pragma unroll
    for (int nt = 0; nt < NT; ++nt) {
      half8 b = w8[(nt * 16 + l15) * 128 + sw];
      acc[0][nt] = __builtin_amdgcn_mfma_f32_16x16x32_f16(a0u.h, b, acc[0][nt], 0, 0, 0);
      acc[1][nt] = __builtin_amdgcn_mfma_f32_16x16x32_f16(a1u.h, b, acc[1][nt], 0, 0, 0);
    }
  }
}

__global__ __launch_bounds__(256, 1) void lstm_persist(
    const float* __restrict__ g0,
    const unsigned short* __restrict__ wbuf,
    const float* __restrict__ b_ih, const float* __restrict__ b_hh,
    const float* __restrict__ b_fc,
    float* __restrict__ out,
    unsigned short* __restrict__ hbuf,   // [2][B][H] fp16 double buffer
    unsigned* __restrict__ ctl) {        // monotonic barrier counter at ctl+64
  extern __shared__ __align__(16) unsigned short sW[];
  const int tid  = threadIdx.x;
  const int wv   = tid >> 6;
  const int lane = tid & 63;
  const int quad = lane >> 4;
  const int l15  = lane & 15;
  const int bid  = blockIdx.x;
  const bool isg = bid < NGB;
  const int rsw  = l15 & 7;

  unsigned* bar = ctl + 64;          // single flat monotonic counter

  { // stage this block's weight slice into LDS (already fp16 + swizzled in wbuf)
    const uint4* s4 = (const uint4*)(wbuf +
        (size_t)(isg ? bid * 64 : NGB * 64 + (bid - NGB) * 16) * HH);
    uint4* d4 = (uint4*)sW;
    const int n16 = (isg ? 64 * HH : 16 * HH) / 8;
    for (int i = tid; i < n16; i += 256) d4[i] = s4[i];
  }
  __syncthreads();
  const half8* w8 = (const half8*)sW;
  const floatx4 z4 = {0.f, 0.f, 0.f, 0.f};

  if (isg) {
    const int u = bid * 16 + l15;   // hidden unit this lane owns (all 4 gates)
    const float bi = b_ih[u]          + b_hh[u];
    const float bf = b_ih[HH + u]     + b_hh[HH + u];
    const float bg = b_ih[2*HH + u]   + b_hh[2*HH + u];
    const float bo = b_ih[3*HH + u]   + b_hh[3*HH + u];
    float c[2][4] = {{0,0,0,0},{0,0,0,0}};

    // ---- t = 0: gates precomputed in g0; c_prev = 0
#pragma unroll
    for (int mt = 0; mt < 2; ++mt)
#pragma unroll
      for (int r = 0; r < 4; ++r) {
        const int m = wv * 32 + mt * 16 + quad * 4 + r;
        const float* gr = g0 + (size_t)m * G4;
        float iv = gr[u], gv = gr[2 * HH + u], ov = gr[3 * HH + u];
        float ct = sigf(iv) * tanhf_fast(gv);
        c[mt][r] = ct;
        store_h(hbuf + (size_t)m * HH + u, sigf(ov) * tanhf_fast(ct));
      }
    stepbar(bar, NB);   // publish h(0)

    const int abase0 = ((wv * 32 +      l15) * 128 + quad) * 2;  // u64 units
    const int abase1 = ((wv * 32 + 16 + l15) * 128 + quad) * 2;

    for (int t = 1; t < TT; ++t) {
      const u64t* hb = (const u64t*)(hbuf + (size_t)((t - 1) & 1) * BB * HH);
      unsigned short* hw = hbuf + (size_t)(t & 1) * BB * HH;
      floatx4 acc[2][4] = {{z4, z4, z4, z4}, {z4, z4, z4, z4}};
      gemm2xNT<4, 16>(hb, w8, abase0, abase1, quad, rsw, l15, acc);
#pragma unroll
      for (int mt = 0; mt < 2; ++mt)
#pragma unroll
        for (int r = 0; r < 4; ++r) {
          float iv = sigf(acc[mt][0][r] + bi);
          float gv = tanhf_fast(acc[mt][1][r] + bg);
          float fv = sigf(acc[mt][2][r] + bf);
          float ov = sigf(acc[mt][3][r] + bo);
          float ct = fv * c[mt][r] + iv * gv;
          c[mt][r] = ct;
          const int m = wv * 32 + mt * 16 + quad * 4 + r;
          store_h(hw + (size_t)m * HH + u, ov * tanhf_fast(ct));
        }
      stepbar(bar, NB * (unsigned)(t + 1));
    }
  } else {
    // fc block: y_{t-1} = h_{t-1} @ W_fc^T + b_fc, overlapped with step-t gate GEMMs
    const int fb = bid - NGB;
    const int pcol = fb * 16 + l15;
    const float biasf = b_fc[pcol];
    const int abase0 = (((wv * 2 + 0) * 16 + l15) * 128 + quad) * 2;  // u64 units
    const int abase1 = (((wv * 2 + 1) * 16 + l15) * 128 + quad) * 2;

    stepbar(bar, NB);   // t = 0: nothing to project yet; wait for h(0)

    for (int t = 1; t <= TT; ++t) {
      const u64t* hb = (const u64t*)(hbuf + (size_t)((t - 1) & 1) * BB * HH);
      floatx4 acc[2][1] = {{z4}, {z4}};
      gemm2xNT<1, 16>(hb, w8, abase0, abase1, quad, rsw, l15, acc);
#pragma unroll
      for (int mt = 0; mt < 2; ++mt)
#pragma unroll
        for (int r = 0; r < 4; ++r) {
          const int m = (wv * 2 + mt) * 16 + quad * 4 + r;
          out[(size_t)m * (TT * PP) + (size_t)(t - 1) * PP + pcol] = acc[mt][0][r] + biasf;
        }
      if (t < TT) stepbar(bar, NB * (unsigned)(t + 1));
    }
  }
}

extern "C" void kernel_launch(void* const* d_in, const int* in_sizes, int n_in,
                              void* d_out, int out_size, void* d_ws, size_t ws_size,
                              hipStream_t stream) {
  const float* z    = (const float*)d_in[1];
  const float* w_ih = (const float*)d_in[2];
  const float* w_hh = (const float*)d_in[3];
  const float* b_ih = (const float*)d_in[4];
  const float* b_hh = (const float*)d_in[5];
  const float* W_fc = (const float*)d_in[6];
  const float* b_fc = (const float*)d_in[7];
  float* out = (float*)d_out;

  // workspace layout (~10.8 MiB total)
  char* ws = (char*)d_ws;
  unsigned*       ctl  = (unsigned*)ws;                                        // 4 KiB ctrl
  unsigned short* hbuf = (unsigned short*)(ws + 4096);                         // 512 KiB
  float*          g0   = (float*)(ws + 4096 + (size_t)2 * BB * HH * 2);        // 2 MiB
  unsigned short* wbuf = (unsigned short*)(ws + 4096 + (size_t)2 * BB * HH * 2
                                              + (size_t)BB * G4 * 4);          // 8.25 MiB

  // allow 128 KiB dynamic LDS (gfx950 has 160 KiB/CU)
  (void)hipFuncSetAttribute(reinterpret_cast<const void*>(lstm_persist),
                            hipFuncAttributeMaxDynamicSharedMemorySize, 160 * 1024);

  hipMemsetAsync(ctl, 0, 4096, stream);
  prep_gates0 <<<dim3(G4), dim3(BB), 0, stream>>>(z, w_ih, b_ih, b_hh, g0);
  prep_weights<<<dim3(NGB * 64 + NFB * 16), dim3(256), 0, stream>>>(w_hh, W_fc, wbuf);
  lstm_persist<<<dim3(NB), dim3(256), 128 * 1024, stream>>>(g0, wbuf, b_ih, b_hh, b_fc,
                                                            out, hbuf, ctl);
}

// Round 3
// 3100.656 us; speedup vs baseline: 1.6686x; 1.6686x over previous
//
#include <hip/hip_runtime.h>
#include <stdint.h>

// Problem constants
#define BB   128      // batch
#define LL   128      // latent dim
#define HH   1024     // hidden
#define G4   4096     // 4*H
#define TT   256      // time steps
#define PP   128      // output cols per step

#define NGB  64                  // gate blocks: each owns 16 hidden units (64 weight rows)
#define NFB  8                   // fc blocks: each owns 16 rows of W_fc
#define NB   (NGB + NFB)

typedef _Float16 half8  __attribute__((ext_vector_type(8)));
typedef float   floatx4 __attribute__((ext_vector_type(4)));

__device__ __forceinline__ float sigf(float x) {
  x = fminf(fmaxf(x, -30.f), 30.f);
  return 1.f / (1.f + __expf(-x));
}
__device__ __forceinline__ float tanhf_fast(float x) {
  x = fminf(fmaxf(x, -15.f), 15.f);
  float e = __expf(2.f * x);
  return (e - 1.f) / (e + 1.f);
}
__device__ __forceinline__ unsigned short f2h(float x) {
  _Float16 h = (_Float16)x;
  return __builtin_bit_cast(unsigned short, h);
}
// agent-scope write-through h store: at LLC once vmcnt(0) drains
__device__ __forceinline__ void store_h(unsigned short* p, float x) {
  __hip_atomic_store(p, f2h(x), __ATOMIC_RELAXED, __HIP_MEMORY_SCOPE_AGENT);
}

// LLC-coherent 16B load: sc0 sc1 -> bypass L1/L2, read at the coherence point
// (where the write-through h stores land). NON-atomic at the IR level, so we
// hand-pipeline it with counted vmcnt below (the compiler refused to pipeline
// r2's relaxed-atomic loads). No allocation in L1/L2 -> nothing can ever go
// stale -> the per-step fence(acquire,"agent") [buffer_inv sc1 = L2 tag walk,
// 9 blocks x 8 XCDs every step] is deleted entirely.
#define ALOAD(dst, base, IMM)                                              \
  asm volatile("global_load_dwordx4 %0, %1, off offset:%2 sc0 sc1"         \
               : "=&v"(dst) : "v"(base), "n"(IMM) : "memory")

// One pipeline stage: wait for pair kc (counted), 2*NT MFMAs, issue pair kc+8.
// The "+v" ties on the consumed ring registers make the MFMAs data-depend on
// the waitcnt (rule #18: MFMA would otherwise hoist past an inline-asm wait).
#define KSTEP(kc, WN)                                                      \
  {                                                                        \
    asm volatile("s_waitcnt vmcnt(%2)"                                     \
                 : "+v"(ap0[(kc) & 7]), "+v"(ap1[(kc) & 7]) : "n"(WN));    \
    half8 a0 = ap0[(kc) & 7], a1 = ap1[(kc) & 7];                          \
    const int sw = ((kc) * 4 + quad) ^ rsw;                                \
    _Pragma("unroll")                                                      \
    for (int nt = 0; nt < NT; ++nt) {                                      \
      half8 b = w8[(nt * 16 + l15) * 128 + sw];                            \
      acc[0][nt] = __builtin_amdgcn_mfma_f32_16x16x32_f16(a0, b, acc[0][nt], 0, 0, 0); \
      acc[1][nt] = __builtin_amdgcn_mfma_f32_16x16x32_f16(a1, b, acc[1][nt], 0, 0, 0); \
    }                                                                      \
    if ((kc) < 24) {                                                       \
      ALOAD(ap0[(kc) & 7], p0, ((kc) + 8) * 64);                           \
      ALOAD(ap1[(kc) & 7], p1, ((kc) + 8) * 64);                           \
    }                                                                      \
  }

// Flat monotonic per-step grid barrier, zero cache-maintenance ops.
// Release: h stores are write-through agent-scope, drained by vmcnt(0) before
// the arrival add. Acquire: not needed — all cross-step reads use sc0sc1
// loads that read at the coherence point.
__device__ __forceinline__ void stepbar(unsigned* bar, unsigned target) {
  __syncthreads();
  if (threadIdx.x == 0) {
    asm volatile("s_waitcnt vmcnt(0)" ::: "memory");   // h stores at LLC
    __hip_atomic_fetch_add(bar, 1u, __ATOMIC_RELAXED, __HIP_MEMORY_SCOPE_AGENT);
    while (__hip_atomic_load(bar, __ATOMIC_RELAXED, __HIP_MEMORY_SCOPE_AGENT) < target)
      __builtin_amdgcn_s_sleep(1);
  }
  __syncthreads();
}

// gates0 = z @ w_ih^T + b_ih + b_hh   (step-0 gates; h0=c0=0, x=0 for t>=1)
__global__ void prep_gates0(const float* __restrict__ z, const float* __restrict__ w_ih,
                            const float* __restrict__ b_ih, const float* __restrict__ b_hh,
                            float* __restrict__ g0) {
  int j = blockIdx.x;     // 0..4095
  int b = threadIdx.x;    // 0..127
  const float* zr = z + b * LL;
  const float* wr = w_ih + (size_t)j * LL;
  float s = 0.f;
#pragma unroll 4
  for (int k = 0; k < LL; ++k) s += zr[k] * wr[k];
  g0[(size_t)b * G4 + j] = s + b_ih[j] + b_hh[j];
}

// Convert w_hh / W_fc to fp16 in the persistent kernel's LDS layout.
// Gate block bid owns units u = bid*16 .. bid*16+15; LDS rows (tile*16+nl) for
// tile 0..3 = gates i,g,f,o of unit nl. Each row's 8-elem k-chunks are
// XOR-swizzled by (nl&7) so the wave's B-reads are same-bank-free.
__global__ void prep_weights(const float* __restrict__ w_hh, const float* __restrict__ W_fc,
                             unsigned short* __restrict__ wbuf) {
  int R = blockIdx.x;                 // 0..4223 (4096 gate rows + 128 fc rows)
  const float* src; int rsw;
  if (R < NGB * 64) {
    int bid = R >> 6, rr = R & 63, tile = rr >> 4, nl = rr & 15;
    int g = (tile == 0) ? 0 : (tile == 1) ? 2 : (tile == 2) ? 1 : 3;  // i,g,f,o
    src = w_hh + (size_t)(g * HH + bid * 16 + nl) * HH;
    rsw = nl & 7;
  } else {
    int p = R - NGB * 64;
    src = W_fc + (size_t)p * HH;
    rsw = p & 7;
  }
  unsigned short* dst = wbuf + (size_t)R * HH;
  for (int k = threadIdx.x; k < HH; k += blockDim.x) {
    int dk = (((k >> 3) ^ rsw) << 3) | (k & 7);
    _Float16 v = (_Float16)src[k];
    dst[dk] = __builtin_bit_cast(unsigned short, v);
  }
}

// One K=1024 MFMA pass: C[2 mtiles x NT ntiles]. A streamed from global h via
// sc0sc1 16B loads (LLC-coherent), hand-pipelined 8-deep per m-stream with
// counted vmcnt. B from LDS (fp16, swizzled).
template <int NT>
__device__ __forceinline__ void gemm2xNT(const unsigned short* __restrict__ hb,
                                         const half8* __restrict__ w8,
                                         int au0, int au1,   // ushort units
                                         int quad, int rsw, int l15,
                                         floatx4 acc[2][NT]) {
  const unsigned short* p0 = hb + au0;
  const unsigned short* p1 = hb + au1;
  half8 ap0[8], ap1[8];
  ALOAD(ap0[0], p0, 0);   ALOAD(ap1[0], p1, 0);
  ALOAD(ap0[1], p0, 64);  ALOAD(ap1[1], p1, 64);
  ALOAD(ap0[2], p0, 128); ALOAD(ap1[2], p1, 128);
  ALOAD(ap0[3], p0, 192); ALOAD(ap1[3], p1, 192);
  ALOAD(ap0[4], p0, 256); ALOAD(ap1[4], p1, 256);
  ALOAD(ap0[5], p0, 320); ALOAD(ap1[5], p1, 320);
  ALOAD(ap0[6], p0, 384); ALOAD(ap1[6], p1, 384);
  ALOAD(ap0[7], p0, 448); ALOAD(ap1[7], p1, 448);
  KSTEP(0, 14)  KSTEP(1, 14)  KSTEP(2, 14)  KSTEP(3, 14)
  KSTEP(4, 14)  KSTEP(5, 14)  KSTEP(6, 14)  KSTEP(7, 14)
  KSTEP(8, 14)  KSTEP(9, 14)  KSTEP(10, 14) KSTEP(11, 14)
  KSTEP(12, 14) KSTEP(13, 14) KSTEP(14, 14) KSTEP(15, 14)
  KSTEP(16, 14) KSTEP(17, 14) KSTEP(18, 14) KSTEP(19, 14)
  KSTEP(20, 14) KSTEP(21, 14) KSTEP(22, 14) KSTEP(23, 14)
  KSTEP(24, 14) KSTEP(25, 12) KSTEP(26, 10) KSTEP(27, 8)
  KSTEP(28, 6)  KSTEP(29, 4)  KSTEP(30, 2)  KSTEP(31, 0)
}

__global__ __launch_bounds__(256, 1) void lstm_persist(
    const float* __restrict__ g0,
    const unsigned short* __restrict__ wbuf,
    const float* __restrict__ b_ih, const float* __restrict__ b_hh,
    const float* __restrict__ b_fc,
    float* __restrict__ out,
    unsigned short* __restrict__ hbuf,   // [2][B][H] fp16 double buffer
    unsigned* __restrict__ ctl) {        // monotonic barrier counter at ctl+64
  extern __shared__ __align__(16) unsigned short sW[];
  const int tid  = threadIdx.x;
  const int wv   = tid >> 6;
  const int lane = tid & 63;
  const int quad = lane >> 4;
  const int l15  = lane & 15;
  const int bid  = blockIdx.x;
  const bool isg = bid < NGB;
  const int rsw  = l15 & 7;

  unsigned* bar = ctl + 64;          // single flat monotonic counter

  { // stage this block's weight slice into LDS (already fp16 + swizzled in wbuf)
    const uint4* s4 = (const uint4*)(wbuf +
        (size_t)(isg ? bid * 64 : NGB * 64 + (bid - NGB) * 16) * HH);
    uint4* d4 = (uint4*)sW;
    const int n16 = (isg ? 64 * HH : 16 * HH) / 8;
    for (int i = tid; i < n16; i += 256) d4[i] = s4[i];
  }
  __syncthreads();
  const half8* w8 = (const half8*)sW;
  const floatx4 z4 = {0.f, 0.f, 0.f, 0.f};

  if (isg) {
    const int u = bid * 16 + l15;   // hidden unit this lane owns (all 4 gates)
    const float bi = b_ih[u]          + b_hh[u];
    const float bf = b_ih[HH + u]     + b_hh[HH + u];
    const float bg = b_ih[2*HH + u]   + b_hh[2*HH + u];
    const float bo = b_ih[3*HH + u]   + b_hh[3*HH + u];
    float c[2][4] = {{0,0,0,0},{0,0,0,0}};

    // ---- t = 0: gates precomputed in g0; c_prev = 0
#pragma unroll
    for (int mt = 0; mt < 2; ++mt)
#pragma unroll
      for (int r = 0; r < 4; ++r) {
        const int m = wv * 32 + mt * 16 + quad * 4 + r;
        const float* gr = g0 + (size_t)m * G4;
        float iv = gr[u], gv = gr[2 * HH + u], ov = gr[3 * HH + u];
        float ct = sigf(iv) * tanhf_fast(gv);
        c[mt][r] = ct;
        store_h(hbuf + (size_t)m * HH + u, sigf(ov) * tanhf_fast(ct));
      }
    stepbar(bar, NB);   // publish h(0)

    const int au0 = (wv * 32 +      l15) * 1024 + quad * 8;  // ushort units
    const int au1 = (wv * 32 + 16 + l15) * 1024 + quad * 8;

    for (int t = 1; t < TT; ++t) {
      const unsigned short* hb = hbuf + (size_t)((t - 1) & 1) * BB * HH;
      unsigned short* hw = hbuf + (size_t)(t & 1) * BB * HH;
      floatx4 acc[2][4] = {{z4, z4, z4, z4}, {z4, z4, z4, z4}};
      gemm2xNT<4>(hb, w8, au0, au1, quad, rsw, l15, acc);
#pragma unroll
      for (int mt = 0; mt < 2; ++mt)
#pragma unroll
        for (int r = 0; r < 4; ++r) {
          float iv = sigf(acc[mt][0][r] + bi);
          float gv = tanhf_fast(acc[mt][1][r] + bg);
          float fv = sigf(acc[mt][2][r] + bf);
          float ov = sigf(acc[mt][3][r] + bo);
          float ct = fv * c[mt][r] + iv * gv;
          c[mt][r] = ct;
          const int m = wv * 32 + mt * 16 + quad * 4 + r;
          store_h(hw + (size_t)m * HH + u, ov * tanhf_fast(ct));
        }
      stepbar(bar, NB * (unsigned)(t + 1));
    }
  } else {
    // fc block: y_{t-1} = h_{t-1} @ W_fc^T + b_fc, overlapped with step-t gate GEMMs
    const int fb = bid - NGB;
    const int pcol = fb * 16 + l15;
    const float biasf = b_fc[pcol];
    const int au0 = ((wv * 2 + 0) * 16 + l15) * 1024 + quad * 8;  // ushort units
    const int au1 = ((wv * 2 + 1) * 16 + l15) * 1024 + quad * 8;

    stepbar(bar, NB);   // t = 0: nothing to project yet; wait for h(0)

    for (int t = 1; t <= TT; ++t) {
      const unsigned short* hb = hbuf + (size_t)((t - 1) & 1) * BB * HH;
      floatx4 acc[2][1] = {{z4}, {z4}};
      gemm2xNT<1>(hb, w8, au0, au1, quad, rsw, l15, acc);
#pragma unroll
      for (int mt = 0; mt < 2; ++mt)
#pragma unroll
        for (int r = 0; r < 4; ++r) {
          const int m = (wv * 2 + mt) * 16 + quad * 4 + r;
          out[(size_t)m * (TT * PP) + (size_t)(t - 1) * PP + pcol] = acc[mt][0][r] + biasf;
        }
      if (t < TT) stepbar(bar, NB * (unsigned)(t + 1));
    }
  }
}

extern "C" void kernel_launch(void* const* d_in, const int* in_sizes, int n_in,
                              void* d_out, int out_size, void* d_ws, size_t ws_size,
                              hipStream_t stream) {
  const float* z    = (const float*)d_in[1];
  const float* w_ih = (const float*)d_in[2];
  const float* w_hh = (const float*)d_in[3];
  const float* b_ih = (const float*)d_in[4];
  const float* b_hh = (const float*)d_in[5];
  const float* W_fc = (const float*)d_in[6];
  const float* b_fc = (const float*)d_in[7];
  float* out = (float*)d_out;

  // workspace layout (~10.8 MiB total)
  char* ws = (char*)d_ws;
  unsigned*       ctl  = (unsigned*)ws;                                        // 4 KiB ctrl
  unsigned short* hbuf = (unsigned short*)(ws + 4096);                         // 512 KiB
  float*          g0   = (float*)(ws + 4096 + (size_t)2 * BB * HH * 2);        // 2 MiB
  unsigned short* wbuf = (unsigned short*)(ws + 4096 + (size_t)2 * BB * HH * 2
                                              + (size_t)BB * G4 * 4);          // 8.25 MiB

  // allow 128 KiB dynamic LDS (gfx950 has 160 KiB/CU)
  (void)hipFuncSetAttribute(reinterpret_cast<const void*>(lstm_persist),
                            hipFuncAttributeMaxDynamicSharedMemorySize, 160 * 1024);

  hipMemsetAsync(ctl, 0, 4096, stream);
  prep_gates0 <<<dim3(G4), dim3(BB), 0, stream>>>(z, w_ih, b_ih, b_hh, g0);
  prep_weights<<<dim3(NGB * 64 + NFB * 16), dim3(256), 0, stream>>>(w_hh, W_fc, wbuf);
  lstm_persist<<<dim3(NB), dim3(256), 128 * 1024, stream>>>(g0, wbuf, b_ih, b_hh, b_fc,
                                                            out, hbuf, ctl);
}